// Round 3
// baseline (356.428 us; speedup 1.0000x reference)
//
#include <hip/hip_runtime.h>
#include <math.h>

// x [B, C, L] f32 -> out [B, C*10] f32 (10 stats per row, laid out stat-major per batch)
constexpr int B = 64;
constexpr int C = 8;
constexpr int L = 131072;
constexpr int ROWS = B * C;              // 512 blocks = 2 blocks/CU
constexpr int BLOCK = 1024;              // 16 waves
constexpr int NWAVES = BLOCK / 64;       // 16
constexpr int VEC_ITERS = L / BLOCK / 4; // 32 float4 per thread
constexpr int UNROLL = 8;                // 8 loads in flight per round

__global__ __launch_bounds__(BLOCK, 2)   // 2 blocks/CU -> 8 waves/SIMD, needs <=64 VGPR
void stat_kernel(const float* __restrict__ x, float* __restrict__ out) {
    const int row = blockIdx.x;
    const int tid = threadIdx.x;

    const float4* __restrict__ xr =
        reinterpret_cast<const float4*>(x + (size_t)row * L);

    // f32 accumulators: per-thread chains are only 128 elements long; the
    // cross-thread combine below is f64, keeping total error ~1e-6 rel.
    float s1 = 0.f, s2 = 0.f, s3 = 0.f, s4 = 0.f, sa = 0.f;
    float mx = -INFINITY, mn = INFINITY;

    for (int k = 0; k < VEC_ITERS; k += UNROLL) {
        float4 v[UNROLL];
        #pragma unroll
        for (int u = 0; u < UNROLL; ++u)
            v[u] = xr[tid + (k + u) * BLOCK];   // coalesced: 1 KB per wave-load

        #pragma unroll
        for (int u = 0; u < UNROLL; ++u) {
            const float f0 = v[u].x, f1 = v[u].y, f2c = v[u].z, f3 = v[u].w;
            {
                float p = f0 * f0;
                s1 += f0; s2 += p;
                s3 = fmaf(p, f0, s3); s4 = fmaf(p, p, s4);
                sa += fabsf(f0);
                mx = fmaxf(mx, f0); mn = fminf(mn, f0);
            }
            {
                float p = f1 * f1;
                s1 += f1; s2 += p;
                s3 = fmaf(p, f1, s3); s4 = fmaf(p, p, s4);
                sa += fabsf(f1);
                mx = fmaxf(mx, f1); mn = fminf(mn, f1);
            }
            {
                float p = f2c * f2c;
                s1 += f2c; s2 += p;
                s3 = fmaf(p, f2c, s3); s4 = fmaf(p, p, s4);
                sa += fabsf(f2c);
                mx = fmaxf(mx, f2c); mn = fminf(mn, f2c);
            }
            {
                float p = f3 * f3;
                s1 += f3; s2 += p;
                s3 = fmaf(p, f3, s3); s4 = fmaf(p, p, s4);
                sa += fabsf(f3);
                mx = fmaxf(mx, f3); mn = fminf(mn, f3);
            }
        }
    }

    // promote to f64 for all cross-thread combining
    double d1 = (double)s1, d2 = (double)s2, d3 = (double)s3,
           d4 = (double)s4, da = (double)sa;

    // ---- wave (64-lane) butterfly reduction ----
    #pragma unroll
    for (int off = 32; off >= 1; off >>= 1) {
        d1 += __shfl_xor(d1, off);
        d2 += __shfl_xor(d2, off);
        d3 += __shfl_xor(d3, off);
        d4 += __shfl_xor(d4, off);
        da += __shfl_xor(da, off);
        mx = fmaxf(mx, __shfl_xor(mx, off));
        mn = fminf(mn, __shfl_xor(mn, off));
    }

    // ---- cross-wave reduction via LDS ----
    __shared__ double ls1[NWAVES], ls2[NWAVES], ls3[NWAVES], ls4[NWAVES], lsa[NWAVES];
    __shared__ float lmx[NWAVES], lmn[NWAVES];

    const int wave = tid >> 6;
    const int lane = tid & 63;
    if (lane == 0) {
        ls1[wave] = d1; ls2[wave] = d2; ls3[wave] = d3; ls4[wave] = d4; lsa[wave] = da;
        lmx[wave] = mx; lmn[wave] = mn;
    }
    __syncthreads();

    if (tid == 0) {
        double t1 = 0, t2 = 0, t3 = 0, t4 = 0, ta = 0;
        float tmx = -INFINITY, tmn = INFINITY;
        #pragma unroll
        for (int w = 0; w < NWAVES; ++w) {
            t1 += ls1[w]; t2 += ls2[w]; t3 += ls3[w]; t4 += ls4[w]; ta += lsa[w];
            tmx = fmaxf(tmx, lmx[w]); tmn = fminf(tmn, lmn[w]);
        }

        const double Ld = (double)L;
        const double mean = t1 / Ld;
        const double rms  = sqrt(t2 / Ld);
        const double var  = (t2 - t1 * t1 / Ld) / (Ld - 1.0);
        const double sd   = sqrt(var);
        const double mu   = mean;
        const double m3 = t3 - 3.0 * mu * t2 + 2.0 * Ld * mu * mu * mu;
        const double m4 = t4 - 4.0 * mu * t3 + 6.0 * mu * mu * t2
                          - 3.0 * Ld * mu * mu * mu * mu;
        const double skew  = m3 / (sd * sd * sd) * Ld / ((Ld - 1.0) * (Ld - 2.0));
        const double kurto = Ld / ((Ld - 1.0) * (Ld - 1.0)) * m4 / (var * var) - 3.0;
        const double meanabs = ta / Ld;
        const double absmax  = fmax(fabs((double)tmx), fabs((double)tmn));
        const double crest   = absmax / rms;
        const double impulse = ((double)tmx - (double)tmn) / meanabs;
        const double shapef  = rms / meanabs;

        const int b = row / C;
        const int c = row % C;
        float* o = out + (size_t)b * (C * 10) + c;
        o[0 * C] = (float)mean;
        o[1 * C] = (float)tmx;
        o[2 * C] = (float)tmn;
        o[3 * C] = (float)rms;
        o[4 * C] = (float)var;
        o[5 * C] = (float)skew;
        o[6 * C] = (float)kurto;
        o[7 * C] = (float)crest;
        o[8 * C] = (float)impulse;
        o[9 * C] = (float)shapef;
    }
}

extern "C" void kernel_launch(void* const* d_in, const int* in_sizes, int n_in,
                              void* d_out, int out_size, void* d_ws, size_t ws_size,
                              hipStream_t stream) {
    const float* x = (const float*)d_in[0];
    float* out = (float*)d_out;
    stat_kernel<<<ROWS, BLOCK, 0, stream>>>(x, out);
}

// Round 5
// 335.585 us; speedup vs baseline: 1.0621x; 1.0621x over previous
//
#include <hip/hip_runtime.h>
#include <math.h>

// x [B, C, L] f32 -> out [B, C*10] f32 (10 stats per row, stat-major per batch)
constexpr int B = 64;
constexpr int C = 8;
constexpr int L = 131072;
constexpr int ROWS = B * C;              // 512 blocks
constexpr int BLOCK = 1024;              // 16 waves/block
constexpr int NWAVES = BLOCK / 64;       // 16
constexpr int VEC_ITERS = L / BLOCK / 4; // 32 float4 per thread
constexpr int UNROLL = 8;                // 8 loads (128 B) in flight per thread

// native clang vector type: accepted by __builtin_nontemporal_load
typedef float vfloat4 __attribute__((ext_vector_type(4)));

// 2nd arg = min waves per SIMD. 8 waves/SIMD with 1024-thread blocks
// = 2 blocks/CU = 32 waves/CU (full), and caps VGPR at 64.
__global__ __launch_bounds__(BLOCK, 8)
void stat_kernel(const float* __restrict__ x, float* __restrict__ out) {
    const int row = blockIdx.x;
    const int tid = threadIdx.x;

    const vfloat4* __restrict__ xr =
        reinterpret_cast<const vfloat4*>(x + (size_t)row * L);

    // f32 accumulators (per-thread chains are 128 elements; cross-thread
    // combine is f64 -> total rel err ~1e-6, threshold is 0.2525).
    float s1 = 0.f, s2 = 0.f, s3 = 0.f, s4 = 0.f, sa = 0.f;
    float mx = -INFINITY, mn = INFINITY;

    for (int k = 0; k < VEC_ITERS; k += UNROLL) {
        vfloat4 v[UNROLL];
        #pragma unroll
        for (int u = 0; u < UNROLL; ++u)
            v[u] = __builtin_nontemporal_load(&xr[tid + (k + u) * BLOCK]);

        #pragma unroll
        for (int u = 0; u < UNROLL; ++u) {
            #pragma unroll
            for (int e = 0; e < 4; ++e) {
                const float f = v[u][e];
                const float p = f * f;
                s1 += f; s2 += p;
                s3 = fmaf(p, f, s3); s4 = fmaf(p, p, s4);
                sa += fabsf(f);
                mx = fmaxf(mx, f); mn = fminf(mn, f);
            }
        }
    }

    // promote to f64 for all cross-thread combining
    double d1 = (double)s1, d2 = (double)s2, d3 = (double)s3,
           d4 = (double)s4, da = (double)sa;

    // ---- wave (64-lane) butterfly reduction ----
    #pragma unroll
    for (int off = 32; off >= 1; off >>= 1) {
        d1 += __shfl_xor(d1, off);
        d2 += __shfl_xor(d2, off);
        d3 += __shfl_xor(d3, off);
        d4 += __shfl_xor(d4, off);
        da += __shfl_xor(da, off);
        mx = fmaxf(mx, __shfl_xor(mx, off));
        mn = fminf(mn, __shfl_xor(mn, off));
    }

    // ---- cross-wave reduction via LDS ----
    __shared__ double ls1[NWAVES], ls2[NWAVES], ls3[NWAVES], ls4[NWAVES], lsa[NWAVES];
    __shared__ float lmx[NWAVES], lmn[NWAVES];

    const int wave = tid >> 6;
    const int lane = tid & 63;
    if (lane == 0) {
        ls1[wave] = d1; ls2[wave] = d2; ls3[wave] = d3; ls4[wave] = d4; lsa[wave] = da;
        lmx[wave] = mx; lmn[wave] = mn;
    }
    __syncthreads();

    if (tid == 0) {
        double t1 = 0, t2 = 0, t3 = 0, t4 = 0, ta = 0;
        float tmx = -INFINITY, tmn = INFINITY;
        #pragma unroll
        for (int w = 0; w < NWAVES; ++w) {
            t1 += ls1[w]; t2 += ls2[w]; t3 += ls3[w]; t4 += ls4[w]; ta += lsa[w];
            tmx = fmaxf(tmx, lmx[w]); tmn = fminf(tmn, lmn[w]);
        }

        const double Ld = (double)L;
        const double mean = t1 / Ld;
        const double rms  = sqrt(t2 / Ld);
        const double var  = (t2 - t1 * t1 / Ld) / (Ld - 1.0);
        const double sd   = sqrt(var);
        const double mu   = mean;
        const double m3 = t3 - 3.0 * mu * t2 + 2.0 * Ld * mu * mu * mu;
        const double m4 = t4 - 4.0 * mu * t3 + 6.0 * mu * mu * t2
                          - 3.0 * Ld * mu * mu * mu * mu;
        const double skew  = m3 / (sd * sd * sd) * Ld / ((Ld - 1.0) * (Ld - 2.0));
        const double kurto = Ld / ((Ld - 1.0) * (Ld - 1.0)) * m4 / (var * var) - 3.0;
        const double meanabs = ta / Ld;
        const double absmax  = fmax(fabs((double)tmx), fabs((double)tmn));
        const double crest   = absmax / rms;
        const double impulse = ((double)tmx - (double)tmn) / meanabs;
        const double shapef  = rms / meanabs;

        const int b = row / C;
        const int c = row % C;
        float* o = out + (size_t)b * (C * 10) + c;
        o[0 * C] = (float)mean;
        o[1 * C] = (float)tmx;
        o[2 * C] = (float)tmn;
        o[3 * C] = (float)rms;
        o[4 * C] = (float)var;
        o[5 * C] = (float)skew;
        o[6 * C] = (float)kurto;
        o[7 * C] = (float)crest;
        o[8 * C] = (float)impulse;
        o[9 * C] = (float)shapef;
    }
}

extern "C" void kernel_launch(void* const* d_in, const int* in_sizes, int n_in,
                              void* d_out, int out_size, void* d_ws, size_t ws_size,
                              hipStream_t stream) {
    const float* x = (const float*)d_in[0];
    float* out = (float*)d_out;
    stat_kernel<<<ROWS, BLOCK, 0, stream>>>(x, out);
}